// Round 9
// baseline (286.418 us; speedup 1.0000x reference)
//
#include <hip/hip_runtime.h>

typedef __bf16 bf16;
typedef __bf16 bf16x8 __attribute__((ext_vector_type(8)));
typedef __bf16 bf16x4 __attribute__((ext_vector_type(4)));
typedef float  f32x4  __attribute__((ext_vector_type(4)));

#define SB2 136        // padded LDS row stride (elems) for generic gemm 128-wide k tiles
#define CUTOFF -18.0

// XOR chunk swizzle for unpadded 128-elem rows (fused kernels).
// chunk' = chunk ^ (row&15) stays in [0,16): provably in-bounds.
__device__ __forceinline__ int swz(int r, int c){
  return r*128 + ((((c>>3) ^ (r&15)) << 3) | (c & 7));
}

__device__ __forceinline__ float silu_f(float x){
  float s = 1.f/(1.f+__expf(-x));
  return x*s;
}
__device__ __forceinline__ float silu_bwd_f(float x){
  float s = 1.f/(1.f+__expf(-x));
  float si = x*s;
  return si + s*(1.f-si);
}

// ===================== generic TMx64 MFMA GEMM (NT), BK=128 =====================
struct MArgs {
  const bf16* A; const bf16* B;
  long sA, sB;
  int lda, ldb;
  int M, N, K;
  int mode;
  float* Cf; long sCf;
  bf16*  Cb; long sCb;
  bf16*  Cb2; long sCb2;
  bf16*  Ct;  long sCt;  int ldct;   // optional transposed output
  int ldc;
  const float* auxf; int ldax; long sAuxf;
  const bf16*  auxb; long sAuxb;
  const float* rowv; long sRowv;
  const double* cd;  long sCd;
  const float* ks;   long sKs;
  const float* clp;  long sClp;
  bf16* Q; bf16* Ko; float* Vo; const float* bqkv;   // mode 11
};

// modes: 1 Cb=acc, Cb2=silu(acc), Ct=silu(acc)^T
//        2 Cb=acc-auxf[r,c], Ct same^T
//        3 Cb=silu_bwd(auxb[r,c])*acc*rowv[r], Ct same^T
//        10 Cf=acc+auxf[r,c]*clv (A scaled by ks[k], dead k-prefix skipped)
//        11 QKV: c<256->Q, <512->Ko (+Ct=Kt), else->Vo (+bias)
template<int TM>
__device__ __forceinline__ void gemm_body(const MArgs& g, int bm, int bn, int bz)
{
  const int row0 = bm*TM, col0 = bn*64;
  constexpr int NI  = TM/32;
  constexpr int TPR = 256/(TM);          // threads per A row (BK=128): TM=64->4, TM=128->2
  constexpr int EPR = 128/TPR;           // elems per thread: 32 or 64
  constexpr int NCH = EPR/8;

  const bf16* A = g.A + (long)bz*g.sA;
  const bf16* B = g.B + (long)bz*g.sB;
  const float* ksp = g.ks ? g.ks + (long)bz*g.sKs : (const float*)0;
  const double* cd = g.cd ? g.cd + (long)bz*g.sCd : (const double*)0;
  float* Cf = g.Cf ? g.Cf + (long)bz*g.sCf : (float*)0;
  bf16* Cb  = g.Cb ? g.Cb + (long)bz*g.sCb : (bf16*)0;
  bf16* Cb2 = g.Cb2 ? g.Cb2 + (long)bz*g.sCb2 : (bf16*)0;
  bf16* Ct  = g.Ct ? g.Ct + (long)bz*g.sCt : (bf16*)0;
  const float* auxf = g.auxf ? g.auxf + (long)bz*g.sAuxf : (const float*)0;
  const bf16*  auxb = g.auxb ? g.auxb + (long)bz*g.sAuxb : (const bf16*)0;
  const float* rowv = g.rowv ? g.rowv + (long)bz*g.sRowv : (const float*)0;

  const int tid = threadIdx.x;
  const int mode = g.mode;
  const int lane = tid & 63;
  const int w = tid >> 6;
  const int wr = (w >> 1) * (TM/2), wc = (w & 1) * 32;
  const int l15 = lane & 15;
  const int quad = lane >> 4;

  __shared__ __align__(16) bf16 As[TM*SB2];
  __shared__ __align__(16) bf16 Bs[64*SB2];

  f32x4 acc[NI][2];
  #pragma unroll
  for (int i=0;i<NI;i++)
    #pragma unroll
    for (int j=0;j<2;j++)
      #pragma unroll
      for (int r=0;r<4;r++) acc[i][j][r] = 0.f;

  const int rowA = tid / TPR, kA = (tid % TPR) * EPR;
  const int rowB = tid >> 2,  kB = (tid & 3) * 32;

  int klo = 0;
  if (cd && ksp) {
    const double cref = cd[g.K-1];
    while (klo + 128 < g.K && (cref - cd[klo+127]) < CUTOFF) klo += 128;
  }

  for (int k0 = klo; k0 < g.K; k0 += 128) {
    {
      const bf16* s = A + (long)(row0+rowA)*g.lda + k0 + kA;
      bf16x8 v[NCH];
      #pragma unroll
      for (int p=0;p<NCH;p++) v[p] = *(const bf16x8*)(s + p*8);
      if (ksp) {
        #pragma unroll
        for (int p=0;p<NCH;p++)
          #pragma unroll
          for (int i=0;i<8;i++)
            v[p][i] = (bf16)((float)v[p][i] * ksp[k0+kA+p*8+i]);
      }
      #pragma unroll
      for (int p=0;p<NCH;p++) *(bf16x8*)&As[rowA*SB2 + kA + p*8] = v[p];
    }
    {
      const bf16* s = B + (long)(col0+rowB)*g.ldb + k0 + kB;
      #pragma unroll
      for (int p=0;p<4;p++) *(bf16x8*)&Bs[rowB*SB2 + kB + p*8] = *(const bf16x8*)(s + p*8);
    }
    __syncthreads();
    #pragma unroll
    for (int ch=0; ch<4; ch++){
      bf16x8 af[NI], bf2[2];
      #pragma unroll
      for (int i=0;i<NI;i++) af[i]  = *(const bf16x8*)&As[(wr + i*16 + l15)*SB2 + ch*32 + quad*8];
      #pragma unroll
      for (int j=0;j<2;j++) bf2[j] = *(const bf16x8*)&Bs[(wc + j*16 + l15)*SB2 + ch*32 + quad*8];
      #pragma unroll
      for (int i=0;i<NI;i++)
        #pragma unroll
        for (int j=0;j<2;j++)
          acc[i][j] = __builtin_amdgcn_mfma_f32_16x16x32_bf16(af[i], bf2[j], acc[i][j], 0, 0, 0);
    }
    __syncthreads();
  }

  float clv = 0.f;
  if (mode == 10) clv = *(g.clp + (long)bz*g.sClp);

  #pragma unroll
  for (int i=0;i<NI;i++){
    const int rb = row0 + wr + i*16 + quad*4;
    #pragma unroll
    for (int j=0;j<2;j++){
      const int c = col0 + wc + j*16 + l15;
      bf16 tv[4]; bool doT = false;
      #pragma unroll
      for (int reg=0; reg<4; reg++){
        const int r = rb + reg;
        float v = acc[i][j][reg];
        const long co = (long)r*g.ldc + c;
        switch (mode) {
          case 1: {
            Cb[co]  = (bf16)v;
            bf16 sv = (bf16)silu_f(v);
            Cb2[co] = sv;
            tv[reg] = sv; doT = true;
          } break;
          case 2: {
            bf16 o = (bf16)(v - auxf[(long)r*g.ldax + c]);
            Cb[co] = o; tv[reg] = o; doT = true;
          } break;
          case 3: {
            bf16 o = (bf16)(silu_bwd_f((float)auxb[(long)r*g.ldax + c]) * v * rowv[r]);
            Cb[co] = o; tv[reg] = o; doT = true;
          } break;
          case 10: {
            Cf[co] = v + auxf[(long)r*g.ldax + c]*clv;
          } break;
          case 11: {
            float o = v + g.bqkv[c];
            if (c < 256)      g.Q [(long)r*256 + c]       = (bf16)o;
            else if (c < 512) { g.Ko[(long)r*256 + (c-256)] = (bf16)o; tv[reg] = (bf16)o; doT = true; }
            else              g.Vo[(long)r*256 + (c-512)] = o;
          } break;
        }
      }
      if (doT && Ct) {
        bf16x4 t4 = { tv[0], tv[1], tv[2], tv[3] };
        if (mode == 11) {
          const int b = rb / g.ldct, l = rb % g.ldct;
          *(bf16x4*)&Ct[(long)b*g.sCt + (long)(c-256)*g.ldct + l] = t4;
        } else {
          *(bf16x4*)&Ct[(long)c*g.ldct + rb] = t4;
        }
      }
    }
  }
}

__global__ __launch_bounds__(256)
void mfma_gemm128(MArgs g){ gemm_body<128>(g, blockIdx.x, blockIdx.y, blockIdx.z); }

__global__ __launch_bounds__(256)
void mfma_gemm64(MArgs g){ gemm_body<64>(g, blockIdx.x, blockIdx.y, blockIdx.z); }

// dual-job W-next: z<4 -> g1 (batch z), z>=4 -> g2 (batch z-4)
__global__ __launch_bounds__(256)
void wnext_gemm(MArgs g1, MArgs g2){
  const int z = blockIdx.z;
  const MArgs& g = (z < 4) ? g1 : g2;
  const int bz = z & 3;
  if ((int)blockIdx.x*128 >= g.M || (int)blockIdx.y*64 >= g.N) return;
  gemm_body<128>(g, blockIdx.x, blockIdx.y, bz);
}

// ===================== fused inner kernel (64m x 128n tiles), BK=128, swizzled LDS ===========
// O = wdc[m]*(A.W^T) + sum_{l-tiles in band} P . B2
// P[m,l] = -(A[m].B1[l]) * exp(cd[m]-cd[l]) * (l<=m) * (ISF2? lr[l]:1)
// ZSPLIT: band tiles strided across z-pairs, fp32 atomic accumulation into Cf (pre-zeroed)
struct FArgs {
  const bf16 *A, *B1, *B2, *W;
  long sA, sB1, sB2, sW;
  int ldb2;
  const double* cd; long sCd;
  const float* colv; long sColv;
  const float* wdc; long sWdc;
  float* Cf; long sCf;
  bf16* Cb; long sCb;
  int ldc;
};

template<int KS128, int ISF2, int ZSPLIT>
__global__ __launch_bounds__(256)
void fused_inner(FArgs g)
{
  const int m0 = blockIdx.x*64, n0 = blockIdx.y*128;
  const int bz   = ZSPLIT ? (blockIdx.z >> 1) : blockIdx.z;
  const int half = ZSPLIT ? (blockIdx.z & 1)  : 0;
  const int K1 = KS128*128;
  const bf16* A  = g.A  + (long)bz*g.sA;
  const bf16* B1 = g.B1 + (long)bz*g.sB1;
  const bf16* B2 = g.B2 + (long)bz*g.sB2;
  const bf16* W  = g.W  + (long)bz*g.sW;
  const double* cd = g.cd + (long)bz*g.sCd;
  const float* colv = ISF2 ? (g.colv + (long)bz*g.sColv) : (const float*)0;
  const float* wdc = g.wdc + (long)bz*g.sWdc;

  // band start (cd decreasing; largest exponent in tile at l = lb+127)
  int lb = 0;
  while (lb + 128 <= m0 && (cd[m0] - cd[lb+127]) < CUTOFF) lb += 128;
  if (ZSPLIT && half == 1 && lb + 128 > m0) return;

  const int tid = threadIdx.x;
  const int lane = tid & 63, w = tid >> 6;
  const int wr = (w>>1)*32, wc = (w&1)*64;
  const int l15 = lane & 15, quad = lane >> 4;
  const int rowA = tid >> 2, kA = (tid & 3) * 32;   // 64 rows x 128k: 4 thr/row
  const int rowB = tid >> 1, kB = (tid & 1) * 64;   // 128 rows x 128k: 2 thr/row

  __shared__ __align__(16) bf16 As[64*128];   // 16 KB
  __shared__ __align__(16) bf16 Bs[128*128];  // 32 KB
  __shared__ __align__(16) bf16 Ps[64*128];   // 16 KB  (total = 64 KB exactly)

  f32x4 O[2][4];
  #pragma unroll
  for (int i=0;i<2;i++)
    #pragma unroll
    for (int j=0;j<4;j++)
      #pragma unroll
      for (int r=0;r<4;r++) O[i][j][r] = 0.f;

  auto stageA = [&](int k0){
    const bf16* s = A + (long)(m0+rowA)*K1 + k0 + kA;
    #pragma unroll
    for (int p=0;p<4;p++)
      *(bf16x8*)&As[swz(rowA, kA + p*8)] = *(const bf16x8*)(s + p*8);
  };
  auto stageB = [&](const bf16* P, int ld, int rbase, int k0){
    const bf16* s = P + (long)(rbase+rowB)*ld + k0 + kB;
    #pragma unroll
    for (int p=0;p<8;p++)
      *(bf16x8*)&Bs[swz(rowB, kB + p*8)] = *(const bf16x8*)(s + p*8);
  };

  // ---- init: O = wdc[m] * (A . W^T)   (half 0 only)
  if (half == 0) {
    for (int ks=0; ks<KS128; ks++){
      stageA(ks*128);
      stageB(W, K1, n0, ks*128);
      __syncthreads();
      #pragma unroll
      for (int ch=0; ch<4; ch++){
        bf16x8 af[2], bfr[4];
        #pragma unroll
        for (int i=0;i<2;i++) af[i]  = *(const bf16x8*)&As[swz(wr + i*16 + l15, ch*32 + quad*8)];
        #pragma unroll
        for (int j=0;j<4;j++) bfr[j] = *(const bf16x8*)&Bs[swz(wc + j*16 + l15, ch*32 + quad*8)];
        #pragma unroll
        for (int i=0;i<2;i++)
          #pragma unroll
          for (int j=0;j<4;j++)
            O[i][j] = __builtin_amdgcn_mfma_f32_16x16x32_bf16(af[i], bfr[j], O[i][j], 0, 0, 0);
      }
      __syncthreads();
    }
    #pragma unroll
    for (int i=0;i<2;i++)
      #pragma unroll
      for (int reg=0; reg<4; reg++){
        const float s = wdc[m0 + wr + i*16 + quad*4 + reg];
        #pragma unroll
        for (int j=0;j<4;j++) O[i][j][reg] *= s;
      }
  }

  // ---- banded l-loop (strided across halves when ZSPLIT)
  const int lstep = ZSPLIT ? 256 : 128;
  for (int l0 = lb + half*128; l0 <= m0; l0 += lstep) {
    f32x4 P[2][4];
    #pragma unroll
    for (int i=0;i<2;i++)
      #pragma unroll
      for (int j=0;j<4;j++)
        #pragma unroll
        for (int r=0;r<4;r++) P[i][j][r] = 0.f;

    // QK phase: B1 rows l0..l0+127
    for (int ks=0; ks<KS128; ks++){
      stageA(ks*128);
      stageB(B1, K1, l0, ks*128);
      __syncthreads();
      #pragma unroll
      for (int ch=0; ch<4; ch++){
        bf16x8 af[2], bfr[4];
        #pragma unroll
        for (int i=0;i<2;i++) af[i]  = *(const bf16x8*)&As[swz(wr + i*16 + l15, ch*32 + quad*8)];
        #pragma unroll
        for (int j=0;j<4;j++) bfr[j] = *(const bf16x8*)&Bs[swz(wc + j*16 + l15, ch*32 + quad*8)];
        #pragma unroll
        for (int i=0;i<2;i++)
          #pragma unroll
          for (int j=0;j<4;j++)
            P[i][j] = __builtin_amdgcn_mfma_f32_16x16x32_bf16(af[i], bfr[j], P[i][j], 0, 0, 0);
      }
      __syncthreads();
    }

    // decay mask -> Ps (swizzled), and stage B2 for PV; one barrier covers both
    {
      float cl[4], lrv[4];
      #pragma unroll
      for (int j=0;j<4;j++){
        const int l = l0 + wc + j*16 + l15;
        cl[j] = (float)cd[l];
        if (ISF2) lrv[j] = colv[l];
      }
      #pragma unroll
      for (int i=0;i<2;i++)
        #pragma unroll
        for (int reg=0; reg<4; reg++){
          const int mloc = wr + i*16 + quad*4 + reg;
          const int m = m0 + mloc;
          const float cm2 = (float)cd[m];
          #pragma unroll
          for (int j=0;j<4;j++){
            const int lloc = wc + j*16 + l15;
            const int l = l0 + lloc;
            float v = -P[i][j][reg] * __expf(cm2 - cl[j]);
            if (ISF2) v *= lrv[j];
            if (l > m) v = 0.f;
            Ps[swz(mloc, lloc)] = (bf16)v;
          }
        }
    }
    stageB(B2, g.ldb2, n0, l0);     // PV B-tile: rows n0.., k = l0..l0+127
    __syncthreads();

    // PV phase: O += Ps . B2-tile  (single BK=128 step)
    #pragma unroll
    for (int ch=0; ch<4; ch++){
      bf16x8 af[2], bfr[4];
      #pragma unroll
      for (int i=0;i<2;i++) af[i]  = *(const bf16x8*)&Ps[swz(wr + i*16 + l15, ch*32 + quad*8)];
      #pragma unroll
      for (int j=0;j<4;j++) bfr[j] = *(const bf16x8*)&Bs[swz(wc + j*16 + l15, ch*32 + quad*8)];
      #pragma unroll
      for (int i=0;i<2;i++)
        #pragma unroll
        for (int j=0;j<4;j++)
          O[i][j] = __builtin_amdgcn_mfma_f32_16x16x32_bf16(af[i], bfr[j], O[i][j], 0, 0, 0);
    }
    __syncthreads();
  }

  // ---- epilogue
  #pragma unroll
  for (int i=0;i<2;i++){
    const int rb = m0 + wr + i*16 + quad*4;
    #pragma unroll
    for (int j=0;j<4;j++){
      const int c = n0 + wc + j*16 + l15;
      #pragma unroll
      for (int reg=0; reg<4; reg++){
        const long co = (long)(rb+reg)*g.ldc + c;
        if (ZSPLIT)     unsafeAtomicAdd(&g.Cf[(long)bz*g.sCf + co], O[i][j][reg]);
        else if (ISF2)  g.Cf[(long)bz*g.sCf + co] = O[i][j][reg];
        else            g.Cb[(long)bz*g.sCb + co] = (bf16)silu_f(O[i][j][reg]);
      }
    }
  }
}

// ===================== helpers =====================
__global__ __launch_bounds__(256)
void conv_multi(const float* __restrict__ a, bf16* __restrict__ oa, long na,
                const float* __restrict__ b, bf16* __restrict__ ob, long nb,
                const float* __restrict__ c, bf16* __restrict__ oc, long nc)
{
  const int job = blockIdx.y;
  const float* src = job==0 ? a : (job==1 ? b : c);
  bf16* dst       = job==0 ? oa : (job==1 ? ob : oc);
  const long n    = job==0 ? na : (job==1 ? nb : nc);
  long i = ((long)blockIdx.x*256 + threadIdx.x)*8;
  if (i >= n) return;
  float4 x = *(const float4*)&src[i];
  float4 y = *(const float4*)&src[i+4];
  bf16x8 o;
  o[0]=(bf16)x.x; o[1]=(bf16)x.y; o[2]=(bf16)x.z; o[3]=(bf16)x.w;
  o[4]=(bf16)y.x; o[5]=(bf16)y.y; o[6]=(bf16)y.z; o[7]=(bf16)y.w;
  *(bf16x8*)&dst[i] = o;
}

// z<3: Wq/Wk/Wv 256x256 -> Wqkvt + z*65536 ; z>=3: W2 batch (z-3), 256x512 -> W2t
__global__ __launch_bounds__(256)
void transpose_multi(const float* __restrict__ Wq, const float* __restrict__ Wk,
                     const float* __restrict__ Wv, bf16* __restrict__ Wqkvt,
                     const float* __restrict__ W2, bf16* __restrict__ W2t, long HD)
{
  __shared__ bf16 t[64][72];
  const int z = blockIdx.z;
  const float* ip; bf16* op; int R, C;
  if (z < 3) {
    if (blockIdx.y >= 4) return;
    ip = z==0 ? Wq : (z==1 ? Wk : Wv);
    op = Wqkvt + (long)z*256*256;
    R = 256; C = 256;
  } else {
    ip = W2 + (long)(z-3)*HD;
    op = W2t + (long)(z-3)*HD;
    R = 256; C = 512;
  }
  const int r0 = blockIdx.x*64, c0 = blockIdx.y*64;
  const int tid = threadIdx.x;
  const int lr_ = tid>>2, lc = (tid&3)*16;
  #pragma unroll
  for (int q=0;q<4;q++){
    float4 a = *(const float4*)&ip[(long)(r0+lr_)*C + c0+lc + q*4];
    t[lr_][lc+q*4+0] = (bf16)a.x; t[lr_][lc+q*4+1] = (bf16)a.y;
    t[lr_][lc+q*4+2] = (bf16)a.z; t[lr_][lc+q*4+3] = (bf16)a.w;
  }
  __syncthreads();
  const int oc = tid>>2, orr = (tid&3)*16;
  bf16x8 u, v;
  #pragma unroll
  for (int i=0;i<8;i++){ u[i] = t[orr+i][oc]; v[i] = t[orr+8+i][oc]; }
  *(bf16x8*)&op[(long)(c0+oc)*R + r0+orr]   = u;
  *(bf16x8*)&op[(long)(c0+oc)*R + r0+orr+8] = v;
}

__global__ __launch_bounds__(256)
void scalar_proj_kernel(const float* __restrict__ x,
                        const float* __restrict__ wlr, const float* __restrict__ blr,
                        const float* __restrict__ wwd, const float* __restrict__ bwd,
                        const float* __restrict__ lbl, const float* __restrict__ lbw,
                        float* __restrict__ lr, float* __restrict__ lw)
{
  const int row  = blockIdx.x*4 + (threadIdx.x >> 6);
  const int lane = threadIdx.x & 63;
  const float4 a = ((const float4*)(x + (long)row*256))[lane];
  const float4 u = ((const float4*)wlr)[lane];
  const float4 w = ((const float4*)wwd)[lane];
  float d1 = a.x*u.x + a.y*u.y + a.z*u.z + a.w*u.w;
  float d2 = a.x*w.x + a.y*w.y + a.z*w.z + a.w*w.w;
  #pragma unroll
  for (int off=32; off; off>>=1) {
    d1 += __shfl_down(d1, off);
    d2 += __shfl_down(d2, off);
  }
  if (lane == 0) {
    float s1 = 1.f/(1.f+expf(-(d1 + blr[0])));
    lr[row] = expf(lbl[0]) * s1;
    float s2 = 1.f/(1.f+expf(-(d2 + bwd[0])));
    lw[row] = logf(1.f - expf(lbw[0]) * s2);
  }
}

// blocks 0..3: per-batch fp64 scan + derived; block 4: bias concat
__global__ __launch_bounds__(256)
void cumsum_kernel(const float* __restrict__ lw, const float* __restrict__ lr,
                   double* __restrict__ cd, float* __restrict__ wdc,
                   float* __restrict__ se1, float* __restrict__ se2, int L,
                   const float* __restrict__ bq, const float* __restrict__ bk,
                   const float* __restrict__ bv, float* __restrict__ bqkv)
{
  const int b = blockIdx.x;
  const int t = threadIdx.x;
  if (b == 4) {
    for (int i = t; i < 768; i += 256)
      bqkv[i] = (i<256) ? bq[i] : ((i<512) ? bk[i-256] : bv[i-512]);
    return;
  }
  const float* lwb = lw + (long)b*L;
  __shared__ double sum_s[256];
  double loc[8];
  double s = 0.0;
  #pragma unroll
  for (int i=0;i<8;i++){ s += (double)lwb[t*8+i]; loc[i] = s; }
  sum_s[t] = s;
  __syncthreads();
  for (int off=1; off<256; off<<=1){
    double v = 0.0;
    if (t >= off) v = sum_s[t-off];
    __syncthreads();
    sum_s[t] += v;
    __syncthreads();
  }
  const double prefix = (t > 0) ? sum_s[t-1] : 0.0;
  const double total  = sum_s[255];
  #pragma unroll
  for (int i=0;i<8;i++){
    double c = prefix + loc[i];
    long idx = (long)b*L + t*8 + i;
    cd[idx]  = c;
    wdc[idx] = (float)exp(c);
    double e = exp(total - c);
    se1[idx] = (float)(-e);
    se2[idx] = (float)(-e) * lr[idx];
  }
}

extern "C" void kernel_launch(void* const* d_in, const int* in_sizes, int n_in,
                              void* d_out, int out_size, void* d_ws, size_t ws_size,
                              hipStream_t stream)
{
  const int Bn = 4, L = 2048, D = 256, H = 512;
  const long LD = (long)L*D, LH = (long)L*H, HD = (long)H*D;

  const float* x   = (const float*)d_in[0];
  const float* W1  = (const float*)d_in[1];
  const float* W2  = (const float*)d_in[2];
  const float* Wq  = (const float*)d_in[3];
  const float* bq  = (const float*)d_in[4];
  const float* Wk  = (const float*)d_in[5];
  const float* bk  = (const float*)d_in[6];
  const float* Wv  = (const float*)d_in[7];
  const float* bv  = (const float*)d_in[8];
  const float* wlr = (const float*)d_in[9];
  const float* blr = (const float*)d_in[10];
  const float* wwd = (const float*)d_in[11];
  const float* bwd = (const float*)d_in[12];
  const float* lbl = (const float*)d_in[13];
  const float* lbw = (const float*)d_in[14];
  (void)in_sizes; (void)n_in; (void)out_size; (void)ws_size;

  float* out0 = (float*)d_out;            // Z2_      [B,L,D]
  float* out1 = out0 + (long)Bn*LD;       // W1_next  [B,H,D]
  float* out2 = out1 + (long)Bn*HD;       // W2_next  [B,D,H]

  char* wsp = (char*)d_ws;
  size_t off = 0;
  auto alloc = [&](size_t bytes)->void*{
    void* p = wsp + off; off += (bytes + 255) & ~(size_t)255; return p;
  };
  bf16* xb    = (bf16*)alloc((size_t)Bn*LD*2);
  bf16* Wqkvt = (bf16*)alloc((size_t)3*D*D*2);
  float* bqkv = (float*)alloc((size_t)3*D*4);
  bf16* W1b  = (bf16*)alloc((size_t)Bn*HD*2);
  bf16* W2b  = (bf16*)alloc((size_t)Bn*HD*2);
  bf16* W2t  = (bf16*)alloc((size_t)Bn*HD*2);
  bf16* Qb   = (bf16*)alloc((size_t)Bn*LD*2);
  bf16* Kb   = (bf16*)alloc((size_t)Bn*LD*2);
  bf16* Kt   = (bf16*)alloc((size_t)Bn*LD*2);
  float* Vf  = (float*)alloc((size_t)Bn*LD*4);
  bf16* Z1b  = (bf16*)alloc((size_t)Bn*LH*2);
  bf16* X2b  = (bf16*)alloc((size_t)Bn*LH*2);
  bf16* X2t  = (bf16*)alloc((size_t)Bn*LH*2);
  bf16* gZb  = (bf16*)alloc((size_t)Bn*LD*2);
  bf16* gZt  = (bf16*)alloc((size_t)Bn*LD*2);
  bf16* A1b  = (bf16*)alloc((size_t)Bn*LH*2);
  bf16* A1t  = (bf16*)alloc((size_t)Bn*LH*2);
  bf16* X2_b = (bf16*)alloc((size_t)Bn*LH*2);
  float* lrb = (float*)alloc((size_t)Bn*L*4);
  float* lwb = (float*)alloc((size_t)Bn*L*4);
  float* wdc = (float*)alloc((size_t)Bn*L*4);
  float* se1 = (float*)alloc((size_t)Bn*L*4);
  float* se2 = (float*)alloc((size_t)Bn*L*4);
  double* cdb = (double*)alloc((size_t)Bn*L*8);

  auto run128 = [&](const MArgs& g, int Z){
    dim3 grid(g.M/128, g.N/64, Z);
    mfma_gemm128<<<grid, 256, 0, stream>>>(g);
  };
  auto run64 = [&](const MArgs& g, int Z){
    dim3 grid(g.M/64, g.N/64, Z);
    mfma_gemm64<<<grid, 256, 0, stream>>>(g);
  };

  // zero out0 (F2 accumulates atomically)
  hipMemsetAsync(out0, 0, (size_t)Bn*LD*4, stream);

  // ---- front matter (merged)
  conv_multi<<<dim3(1024,3), 256, 0, stream>>>(x, xb, Bn*LD, W1, W1b, Bn*HD, W2, W2b, Bn*HD);
  transpose_multi<<<dim3(4,8,7), 256, 0, stream>>>(Wq, Wk, Wv, Wqkvt, W2, W2t, HD);
  scalar_proj_kernel<<<dim3(Bn*L/4), 256, 0, stream>>>(x, wlr, blr, wwd, bwd, lbl, lbw, lrb, lwb);
  cumsum_kernel<<<dim3(5), 256, 0, stream>>>(lwb, lrb, cdb, wdc, se1, se2, L, bq, bk, bv, bqkv);

  // ---- fused QKV (M = B*L, N = 768); Kt via Ct
  {
    MArgs g{}; g.A = xb; g.lda = D; g.B = Wqkvt; g.ldb = D;
    g.M = Bn*L; g.N = 3*D; g.K = D; g.mode = 11; g.ldc = 0;
    g.Q = Qb; g.Ko = Kb; g.Vo = Vf; g.bqkv = bqkv;
    g.Ct = Kt; g.sCt = LD; g.ldct = L;
    run128(g, 1);
  }
  // ---- Z1 = K.W1^T ; X2 = silu(Z1); X2t via Ct
  {
    MArgs g{}; g.A = Kb; g.lda = D; g.sA = LD; g.B = W1b; g.ldb = D; g.sB = HD;
    g.M = L; g.N = H; g.K = D; g.mode = 1; g.ldc = H;
    g.Cb = Z1b; g.sCb = LH; g.Cb2 = X2b; g.sCb2 = LH;
    g.Ct = X2t; g.sCt = LH; g.ldct = L; run64(g, Bn);
  }
  // ---- gZ2 = X2.W2^T - V; gZt via Ct
  {
    MArgs g{}; g.A = X2b; g.lda = H; g.sA = LH; g.B = W2b; g.ldb = H; g.sB = HD;
    g.M = L; g.N = D; g.K = H; g.mode = 2; g.ldc = D;
    g.auxf = Vf; g.ldax = D; g.sAuxf = LD; g.Cb = gZb; g.sCb = LD;
    g.Ct = gZt; g.sCt = LD; g.ldct = L; run64(g, Bn);
  }
  // ---- A1 = silu_bwd(Z1)*(gZ2.W2)*lr; A1t via Ct
  {
    MArgs g{}; g.A = gZb; g.lda = D; g.sA = LD; g.B = W2t; g.ldb = D; g.sB = HD;
    g.M = L; g.N = H; g.K = D; g.mode = 3; g.ldc = H;
    g.auxb = Z1b; g.ldax = H; g.sAuxb = LH; g.rowv = lrb; g.sRowv = L;
    g.Cb = A1b; g.sCb = LH;
    g.Ct = A1t; g.sCt = LH; g.ldct = L; run64(g, Bn);
  }
  // ---- F1: X2_ = silu( wdc[m]*(Q.W1^T) + sum_l P1.A1 )
  {
    FArgs f{};
    f.A = Qb;  f.sA = LD;  f.B1 = Kb;  f.sB1 = LD;
    f.B2 = A1t; f.sB2 = LH; f.ldb2 = L;
    f.W = W1b; f.sW = HD;
    f.cd = cdb; f.sCd = L; f.wdc = wdc; f.sWdc = L;
    f.Cb = X2_b; f.sCb = LH; f.ldc = H;
    fused_inner<2,0,0><<<dim3(L/64, H/128, Bn), 256, 0, stream>>>(f);
  }
  // ---- F2: out0 += wdc[m]*(X2_.W2^T) + sum_l P2.gZ2   (z-split band, atomic)
  {
    FArgs f{};
    f.A = X2_b; f.sA = LH; f.B1 = X2b; f.sB1 = LH;
    f.B2 = gZt; f.sB2 = LD; f.ldb2 = L;
    f.W = W2b; f.sW = HD;
    f.cd = cdb; f.sCd = L; f.colv = lrb; f.sColv = L; f.wdc = wdc; f.sWdc = L;
    f.Cf = out0; f.sCf = LD; f.ldc = D;
    fused_inner<4,1,1><<<dim3(L/64, D/128, Bn*2), 256, 0, stream>>>(f);
  }
  // ---- W1_next + W2_next in one launch
  {
    MArgs g1{}; g1.A = A1t; g1.lda = L; g1.sA = LH; g1.B = Kt; g1.ldb = L; g1.sB = LD;
    g1.M = H; g1.N = D; g1.K = L; g1.mode = 10; g1.ldc = D;
    g1.ks = se1; g1.sKs = L; g1.cd = cdb; g1.sCd = L;
    g1.auxf = W1; g1.ldax = D; g1.sAuxf = HD; g1.clp = wdc + (L-1); g1.sClp = L;
    g1.Cf = out1; g1.sCf = HD;

    MArgs g2{}; g2.A = gZt; g2.lda = L; g2.sA = LD; g2.B = X2t; g2.ldb = L; g2.sB = LH;
    g2.M = D; g2.N = H; g2.K = L; g2.mode = 10; g2.ldc = H;
    g2.ks = se2; g2.sKs = L; g2.cd = cdb; g2.sCd = L;
    g2.auxf = W2; g2.ldax = H; g2.sAuxf = HD; g2.clp = wdc + (L-1); g2.sClp = L;
    g2.Cf = out2; g2.sCf = HD;

    wnext_gemm<<<dim3(4,8,8), 256, 0, stream>>>(g1, g2);
  }
}

// Round 10
// 240.667 us; speedup vs baseline: 1.1901x; 1.1901x over previous
//
#include <hip/hip_runtime.h>

typedef __bf16 bf16;
typedef __bf16 bf16x8 __attribute__((ext_vector_type(8)));
typedef __bf16 bf16x4 __attribute__((ext_vector_type(4)));
typedef float  f32x4  __attribute__((ext_vector_type(4)));

#define SB 72    // LDS row stride (elems) for 64-wide k tiles
#define CUTOFF -18.0

__device__ __forceinline__ float silu_f(float x){
  float s = 1.f/(1.f+__expf(-x));
  return x*s;
}
__device__ __forceinline__ float silu_bwd_f(float x){
  float s = 1.f/(1.f+__expf(-x));
  float si = x*s;
  return si + s*(1.f-si);
}

// ===================== generic TMx64 MFMA GEMM (NT), BK=64 (R8-proven) =====================
struct MArgs {
  const bf16* A; const bf16* B;
  long sA, sB;
  int lda, ldb;
  int M, N, K;
  int mode;
  float* Cf; long sCf;
  bf16*  Cb; long sCb;
  bf16*  Cb2; long sCb2;
  bf16*  Ct;  long sCt;  int ldct;   // optional transposed output
  int ldc;
  const float* auxf; int ldax; long sAuxf;
  const bf16*  auxb; long sAuxb;
  const float* rowv; long sRowv;
  const double* cd;  long sCd;
  const float* ks;   long sKs;
  const float* clp;  long sClp;
  bf16* Q; bf16* Ko; float* Vo; const float* bqkv;   // mode 11
};

// modes: 1 Cb=acc, Cb2=silu(acc), Ct=silu(acc)^T
//        2 Cb=acc-auxf[r,c], Ct same^T
//        3 Cb=silu_bwd(auxb[r,c])*acc*rowv[r], Ct same^T
//        10 Cf=acc+auxf[r,c]*clv (A scaled by ks[k], dead k-prefix skipped)
//        11 QKV: c<256->Q, <512->Ko (+Ct=Kt), else->Vo (+bias)
template<int TM>
__device__ __forceinline__ void gemm_body(const MArgs& g, int bm, int bn, int bz)
{
  const int row0 = bm*TM, col0 = bn*64;
  constexpr int NI  = TM/32;
  constexpr int TPR = 256/TM;
  constexpr int EPR = 64/TPR;
  constexpr int NCH = EPR/8;

  const bf16* A = g.A + (long)bz*g.sA;
  const bf16* B = g.B + (long)bz*g.sB;
  const float* ksp = g.ks ? g.ks + (long)bz*g.sKs : (const float*)0;
  const double* cd = g.cd ? g.cd + (long)bz*g.sCd : (const double*)0;
  float* Cf = g.Cf ? g.Cf + (long)bz*g.sCf : (float*)0;
  bf16* Cb  = g.Cb ? g.Cb + (long)bz*g.sCb : (bf16*)0;
  bf16* Cb2 = g.Cb2 ? g.Cb2 + (long)bz*g.sCb2 : (bf16*)0;
  bf16* Ct  = g.Ct ? g.Ct + (long)bz*g.sCt : (bf16*)0;
  const float* auxf = g.auxf ? g.auxf + (long)bz*g.sAuxf : (const float*)0;
  const bf16*  auxb = g.auxb ? g.auxb + (long)bz*g.sAuxb : (const bf16*)0;
  const float* rowv = g.rowv ? g.rowv + (long)bz*g.sRowv : (const float*)0;

  const int tid = threadIdx.x;
  const int mode = g.mode;
  const int lane = tid & 63;
  const int w = tid >> 6;
  const int wr = (w >> 1) * (TM/2), wc = (w & 1) * 32;
  const int l15 = lane & 15;
  const int quad = lane >> 4;

  __shared__ __align__(16) bf16 As[TM*SB];
  __shared__ __align__(16) bf16 Bs[64*SB];

  f32x4 acc[NI][2];
  #pragma unroll
  for (int i=0;i<NI;i++)
    #pragma unroll
    for (int j=0;j<2;j++)
      #pragma unroll
      for (int r=0;r<4;r++) acc[i][j][r] = 0.f;

  const int rowA = tid / TPR, kA = (tid % TPR) * EPR;
  const int rowB = tid >> 2,  kB = (tid & 3) * 16;

  int klo = 0;
  if (cd && ksp) {
    const double cref = cd[g.K-1];
    while (klo + 64 < g.K && (cref - cd[klo+63]) < CUTOFF) klo += 64;
  }

  for (int k0 = klo; k0 < g.K; k0 += 64) {
    {
      const bf16* s = A + (long)(row0+rowA)*g.lda + k0 + kA;
      bf16x8 v[NCH];
      #pragma unroll
      for (int p=0;p<NCH;p++) v[p] = *(const bf16x8*)(s + p*8);
      if (ksp) {
        #pragma unroll
        for (int p=0;p<NCH;p++)
          #pragma unroll
          for (int i=0;i<8;i++)
            v[p][i] = (bf16)((float)v[p][i] * ksp[k0+kA+p*8+i]);
      }
      #pragma unroll
      for (int p=0;p<NCH;p++) *(bf16x8*)&As[rowA*SB + kA + p*8] = v[p];
    }
    {
      const bf16* s = B + (long)(col0+rowB)*g.ldb + k0 + kB;
      *(bf16x8*)&Bs[rowB*SB + kB]     = *(const bf16x8*)s;
      *(bf16x8*)&Bs[rowB*SB + kB + 8] = *(const bf16x8*)(s+8);
    }
    __syncthreads();
    #pragma unroll
    for (int ch=0; ch<2; ch++){
      bf16x8 af[NI], bf2[2];
      #pragma unroll
      for (int i=0;i<NI;i++) af[i]  = *(const bf16x8*)&As[(wr + i*16 + l15)*SB + ch*32 + quad*8];
      #pragma unroll
      for (int j=0;j<2;j++) bf2[j] = *(const bf16x8*)&Bs[(wc + j*16 + l15)*SB + ch*32 + quad*8];
      #pragma unroll
      for (int i=0;i<NI;i++)
        #pragma unroll
        for (int j=0;j<2;j++)
          acc[i][j] = __builtin_amdgcn_mfma_f32_16x16x32_bf16(af[i], bf2[j], acc[i][j], 0, 0, 0);
    }
    __syncthreads();
  }

  float clv = 0.f;
  if (mode == 10) clv = *(g.clp + (long)bz*g.sClp);

  #pragma unroll
  for (int i=0;i<NI;i++){
    const int rb = row0 + wr + i*16 + quad*4;
    #pragma unroll
    for (int j=0;j<2;j++){
      const int c = col0 + wc + j*16 + l15;
      bf16 tv[4]; bool doT = false;
      #pragma unroll
      for (int reg=0; reg<4; reg++){
        const int r = rb + reg;
        float v = acc[i][j][reg];
        const long co = (long)r*g.ldc + c;
        switch (mode) {
          case 1: {
            Cb[co]  = (bf16)v;
            bf16 sv = (bf16)silu_f(v);
            Cb2[co] = sv;
            tv[reg] = sv; doT = true;
          } break;
          case 2: {
            bf16 o = (bf16)(v - auxf[(long)r*g.ldax + c]);
            Cb[co] = o; tv[reg] = o; doT = true;
          } break;
          case 3: {
            bf16 o = (bf16)(silu_bwd_f((float)auxb[(long)r*g.ldax + c]) * v * rowv[r]);
            Cb[co] = o; tv[reg] = o; doT = true;
          } break;
          case 10: {
            Cf[co] = v + auxf[(long)r*g.ldax + c]*clv;
          } break;
          case 11: {
            float o = v + g.bqkv[c];
            if (c < 256)      g.Q [(long)r*256 + c]       = (bf16)o;
            else if (c < 512) { g.Ko[(long)r*256 + (c-256)] = (bf16)o; tv[reg] = (bf16)o; doT = true; }
            else              g.Vo[(long)r*256 + (c-512)] = o;
          } break;
        }
      }
      if (doT && Ct) {
        bf16x4 t4 = { tv[0], tv[1], tv[2], tv[3] };
        if (mode == 11) {
          const int b = rb / g.ldct, l = rb % g.ldct;
          *(bf16x4*)&Ct[(long)b*g.sCt + (long)(c-256)*g.ldct + l] = t4;
        } else {
          *(bf16x4*)&Ct[(long)c*g.ldct + rb] = t4;
        }
      }
    }
  }
}

__global__ __launch_bounds__(256)
void mfma_gemm128(MArgs g){ gemm_body<128>(g, blockIdx.x, blockIdx.y, blockIdx.z); }

__global__ __launch_bounds__(256)
void mfma_gemm64(MArgs g){ gemm_body<64>(g, blockIdx.x, blockIdx.y, blockIdx.z); }

// dual-job W-next: z<4 -> g1 (batch z), z>=4 -> g2 (batch z-4)
__global__ __launch_bounds__(256)
void wnext_gemm(MArgs g1, MArgs g2){
  const int z = blockIdx.z;
  const MArgs& g = (z < 4) ? g1 : g2;
  const int bz = z & 3;
  if ((int)blockIdx.x*128 >= g.M || (int)blockIdx.y*64 >= g.N) return;
  gemm_body<128>(g, blockIdx.x, blockIdx.y, bz);
}

// ===================== banded P producer (64m x 128l tiles) =====================
// P[m,l] = -(A[m].B1[l]) * exp(cd[m]-cd[l]) * (l<=m) * (ISLR? lr[l]:1)
// Tile slot: l0 = (m0 & ~127) - slot*128. Dead tiles skipped (same test as consumer).
struct PArgs {
  const bf16 *A, *B1;
  long sA, sB1;
  const double* cd; long sCd;
  const float* lrv; long sLr;
  bf16* P;
};

template<int KS64, int ISLR>
__global__ __launch_bounds__(256)
void pgen(PArgs g)
{
  const int mt = blockIdx.x, slot = blockIdx.y, bz = blockIdx.z;
  const int m0 = mt*64;
  const int l0 = (m0 & ~127) - slot*128;
  if (l0 < 0) return;
  const double* cd = g.cd + (long)bz*g.sCd;
  const int lref = (l0+127 < m0) ? (l0+127) : m0;
  if (cd[m0] - cd[lref] < CUTOFF) return;

  const int K1 = KS64*64;
  const bf16* A  = g.A  + (long)bz*g.sA;
  const bf16* B1 = g.B1 + (long)bz*g.sB1;
  const float* lrv = ISLR ? (g.lrv + (long)bz*g.sLr) : (const float*)0;

  const int tid = threadIdx.x;
  const int lane = tid & 63, w = tid >> 6;
  const int wr = (w>>1)*32, wc = (w&1)*64;
  const int l15 = lane & 15, quad = lane >> 4;
  const int rowA = tid >> 2, kA = (tid & 3) * 16;   // 64 rows, 16 elems/thr
  const int rowB = tid >> 1, kB = (tid & 1) * 32;   // 128 rows, 32 elems/thr

  __shared__ __align__(16) bf16 As[64*SB];
  __shared__ __align__(16) bf16 Bs[128*SB];

  f32x4 O[2][4];
  #pragma unroll
  for (int i=0;i<2;i++)
    #pragma unroll
    for (int j=0;j<4;j++)
      #pragma unroll
      for (int r=0;r<4;r++) O[i][j][r] = 0.f;

  for (int ks=0; ks<KS64; ks++){
    const int k0 = ks*64;
    {
      const bf16* s = A + (long)(m0+rowA)*K1 + k0 + kA;
      *(bf16x8*)&As[rowA*SB + kA]     = *(const bf16x8*)s;
      *(bf16x8*)&As[rowA*SB + kA + 8] = *(const bf16x8*)(s+8);
    }
    {
      const bf16* s = B1 + (long)(l0+rowB)*K1 + k0 + kB;
      #pragma unroll
      for (int p=0;p<4;p++) *(bf16x8*)&Bs[rowB*SB + kB + p*8] = *(const bf16x8*)(s + p*8);
    }
    __syncthreads();
    #pragma unroll
    for (int ch=0; ch<2; ch++){
      bf16x8 af[2], bfr[4];
      #pragma unroll
      for (int i=0;i<2;i++) af[i]  = *(const bf16x8*)&As[(wr + i*16 + l15)*SB + ch*32 + quad*8];
      #pragma unroll
      for (int j=0;j<4;j++) bfr[j] = *(const bf16x8*)&Bs[(wc + j*16 + l15)*SB + ch*32 + quad*8];
      #pragma unroll
      for (int i=0;i<2;i++)
        #pragma unroll
        for (int j=0;j<4;j++)
          O[i][j] = __builtin_amdgcn_mfma_f32_16x16x32_bf16(af[i], bfr[j], O[i][j], 0, 0, 0);
    }
    __syncthreads();
  }

  bf16* Pt = g.P + (((long)bz*32 + mt)*3 + slot) * (64*128);
  float cl[4], lv[4];
  #pragma unroll
  for (int j=0;j<4;j++){
    const int l = l0 + wc + j*16 + l15;
    cl[j] = (float)cd[l];
    if (ISLR) lv[j] = lrv[l];
  }
  #pragma unroll
  for (int i=0;i<2;i++)
    #pragma unroll
    for (int reg=0; reg<4; reg++){
      const int mloc = wr + i*16 + quad*4 + reg;
      const int m = m0 + mloc;
      const float cm = (float)cd[m];
      #pragma unroll
      for (int j=0;j<4;j++){
        const int lloc = wc + j*16 + l15;
        const int l = l0 + lloc;
        float v = -O[i][j][reg] * __expf(cm - cl[j]);
        if (ISLR) v *= lv[j];
        if (l > m) v = 0.f;
        Pt[mloc*128 + lloc] = (bf16)v;
      }
    }
}

// ===================== consumer: O = wdc[m]*(A.W^T) + sum_slots P.B2 ====================
// 64m x 128n. ZSPLIT: half0 = cross term, half1 = band term, fp32 atomic into Cf.
struct CArgs {
  const bf16 *A, *W, *P, *B2;
  long sA, sW, sB2;
  int ldb2;
  const double* cd; long sCd;
  const float* wdc; long sWdc;
  float* Cf; long sCf;
  bf16* Cb; long sCb;
  int ldc;
};

template<int KS64, int SILU, int ZSPLIT>
__global__ __launch_bounds__(256)
void cons(CArgs g)
{
  const int mt = blockIdx.x;
  const int m0 = mt*64, n0 = blockIdx.y*128;
  const int bz   = ZSPLIT ? (blockIdx.z >> 1) : blockIdx.z;
  const int half = ZSPLIT ? (blockIdx.z & 1)  : 0;
  const int K1 = KS64*64;
  const bf16* A  = g.A  + (long)bz*g.sA;
  const bf16* W  = g.W  + (long)bz*g.sW;
  const bf16* B2 = g.B2 + (long)bz*g.sB2;
  const double* cd = g.cd + (long)bz*g.sCd;
  const float* wdc = g.wdc + (long)bz*g.sWdc;

  const int tid = threadIdx.x;
  const int lane = tid & 63, w = tid >> 6;
  const int wr = (w>>1)*32, wc = (w&1)*64;
  const int l15 = lane & 15, quad = lane >> 4;
  const int rowA = tid >> 2, kA = (tid & 3) * 16;
  const int rowB = tid >> 1, kB = (tid & 1) * 32;

  // which band slots are alive (block-uniform)
  bool alive[3];
  int nalive = 0;
  #pragma unroll
  for (int s=0;s<3;s++){
    const int l0 = (m0 & ~127) - s*128;
    bool a = (l0 >= 0);
    if (a) {
      const int lref = (l0+127 < m0) ? (l0+127) : m0;
      a = (cd[m0] - cd[lref] >= CUTOFF);
    }
    alive[s] = a; nalive += a ? 1 : 0;
  }
  if (ZSPLIT && half == 1 && nalive == 0) return;

  __shared__ __align__(16) bf16 As[64*SB];
  __shared__ __align__(16) bf16 Bs[128*SB];

  f32x4 O[2][4];
  #pragma unroll
  for (int i=0;i<2;i++)
    #pragma unroll
    for (int j=0;j<4;j++)
      #pragma unroll
      for (int r=0;r<4;r++) O[i][j][r] = 0.f;

  // ---- cross phase: O = A . W^T, scaled by wdc[m]
  if (half == 0) {
    for (int ks=0; ks<KS64; ks++){
      const int k0 = ks*64;
      {
        const bf16* s = A + (long)(m0+rowA)*K1 + k0 + kA;
        *(bf16x8*)&As[rowA*SB + kA]     = *(const bf16x8*)s;
        *(bf16x8*)&As[rowA*SB + kA + 8] = *(const bf16x8*)(s+8);
      }
      {
        const bf16* s = W + (long)(n0+rowB)*K1 + k0 + kB;
        #pragma unroll
        for (int p=0;p<4;p++) *(bf16x8*)&Bs[rowB*SB + kB + p*8] = *(const bf16x8*)(s + p*8);
      }
      __syncthreads();
      #pragma unroll
      for (int ch=0; ch<2; ch++){
        bf16x8 af[2], bfr[4];
        #pragma unroll
        for (int i=0;i<2;i++) af[i]  = *(const bf16x8*)&As[(wr + i*16 + l15)*SB + ch*32 + quad*8];
        #pragma unroll
        for (int j=0;j<4;j++) bfr[j] = *(const bf16x8*)&Bs[(wc + j*16 + l15)*SB + ch*32 + quad*8];
        #pragma unroll
        for (int i=0;i<2;i++)
          #pragma unroll
          for (int j=0;j<4;j++)
            O[i][j] = __builtin_amdgcn_mfma_f32_16x16x32_bf16(af[i], bfr[j], O[i][j], 0, 0, 0);
      }
      __syncthreads();
    }
    #pragma unroll
    for (int i=0;i<2;i++)
      #pragma unroll
      for (int reg=0; reg<4; reg++){
        const float s = wdc[m0 + wr + i*16 + quad*4 + reg];
        #pragma unroll
        for (int j=0;j<4;j++) O[i][j][reg] *= s;
      }
  }

  // ---- band phase: O += P . B2
  if (!ZSPLIT || half == 1) {
    for (int s=0; s<3; s++){
      if (!alive[s]) continue;
      const int l0 = (m0 & ~127) - s*128;
      const bf16* Pt = g.P + (((long)bz*32 + mt)*3 + s) * (64*128);
      for (int hk=0; hk<2; hk++){
        {
          const bf16* sp = Pt + (long)rowA*128 + hk*64 + kA;
          *(bf16x8*)&As[rowA*SB + kA]     = *(const bf16x8*)sp;
          *(bf16x8*)&As[rowA*SB + kA + 8] = *(const bf16x8*)(sp+8);
        }
        {
          const bf16* sp = B2 + (long)(n0+rowB)*g.ldb2 + l0 + hk*64 + kB;
          #pragma unroll
          for (int p=0;p<4;p++) *(bf16x8*)&Bs[rowB*SB + kB + p*8] = *(const bf16x8*)(sp + p*8);
        }
        __syncthreads();
        #pragma unroll
        for (int ch=0; ch<2; ch++){
          bf16x8 af[2], bfr[4];
          #pragma unroll
          for (int i=0;i<2;i++) af[i]  = *(const bf16x8*)&As[(wr + i*16 + l15)*SB + ch*32 + quad*8];
          #pragma unroll
          for (int j=0;j<4;j++) bfr[j] = *(const bf16x8*)&Bs[(wc + j*16 + l15)*SB + ch*32 + quad*8];
          #pragma unroll
          for (int i=0;i<2;i++)
            #pragma unroll
            for (int j=0;j<4;j++)
              O[i][j] = __builtin_amdgcn_mfma_f32_16x16x32_bf16(af[i], bfr[j], O[i][j], 0, 0, 0);
        }
        __syncthreads();
      }
    }
  }

  // ---- epilogue
  #pragma unroll
  for (int i=0;i<2;i++){
    const int rb = m0 + wr + i*16 + quad*4;
    #pragma unroll
    for (int j=0;j<4;j++){
      const int c = n0 + wc + j*16 + l15;
      #pragma unroll
      for (int reg=0; reg<4; reg++){
        const long co = (long)(rb+reg)*g.ldc + c;
        if (ZSPLIT)     unsafeAtomicAdd(&g.Cf[(long)bz*g.sCf + co], O[i][j][reg]);
        else if (SILU)  g.Cb[(long)bz*g.sCb + co] = (bf16)silu_f(O[i][j][reg]);
        else            g.Cf[(long)bz*g.sCf + co] = O[i][j][reg];
      }
    }
  }
}

// ===================== helpers =====================
__global__ __launch_bounds__(256)
void conv_multi(const float* __restrict__ a, bf16* __restrict__ oa, long na,
                const float* __restrict__ b, bf16* __restrict__ ob, long nb,
                const float* __restrict__ c, bf16* __restrict__ oc, long nc)
{
  const int job = blockIdx.y;
  const float* src = job==0 ? a : (job==1 ? b : c);
  bf16* dst       = job==0 ? oa : (job==1 ? ob : oc);
  const long n    = job==0 ? na : (job==1 ? nb : nc);
  long i = ((long)blockIdx.x*256 + threadIdx.x)*8;
  if (i >= n) return;
  float4 x = *(const float4*)&src[i];
  float4 y = *(const float4*)&src[i+4];
  bf16x8 o;
  o[0]=(bf16)x.x; o[1]=(bf16)x.y; o[2]=(bf16)x.z; o[3]=(bf16)x.w;
  o[4]=(bf16)y.x; o[5]=(bf16)y.y; o[6]=(bf16)y.z; o[7]=(bf16)y.w;
  *(bf16x8*)&dst[i] = o;
}

// z<3: Wq/Wk/Wv 256x256 -> Wqkvt + z*65536 ; z>=3: W2 batch (z-3), 256x512 -> W2t
__global__ __launch_bounds__(256)
void transpose_multi(const float* __restrict__ Wq, const float* __restrict__ Wk,
                     const float* __restrict__ Wv, bf16* __restrict__ Wqkvt,
                     const float* __restrict__ W2, bf16* __restrict__ W2t, long HD)
{
  __shared__ bf16 t[64][72];
  const int z = blockIdx.z;
  const float* ip; bf16* op; int R, C;
  if (z < 3) {
    if (blockIdx.y >= 4) return;
    ip = z==0 ? Wq : (z==1 ? Wk : Wv);
    op = Wqkvt + (long)z*256*256;
    R = 256; C = 256;
  } else {
    ip = W2 + (long)(z-3)*HD;
    op = W2t + (long)(z-3)*HD;
    R = 256; C = 512;
  }
  const int r0 = blockIdx.x*64, c0 = blockIdx.y*64;
  const int tid = threadIdx.x;
  const int lr_ = tid>>2, lc = (tid&3)*16;
  #pragma unroll
  for (int q=0;q<4;q++){
    float4 a = *(const float4*)&ip[(long)(r0+lr_)*C + c0+lc + q*4];
    t[lr_][lc+q*4+0] = (bf16)a.x; t[lr_][lc+q*4+1] = (bf16)a.y;
    t[lr_][lc+q*4+2] = (bf16)a.z; t[lr_][lc+q*4+3] = (bf16)a.w;
  }
  __syncthreads();
  const int oc = tid>>2, orr = (tid&3)*16;
  bf16x8 u, v;
  #pragma unroll
  for (int i=0;i<8;i++){ u[i] = t[orr+i][oc]; v[i] = t[orr+8+i][oc]; }
  *(bf16x8*)&op[(long)(c0+oc)*R + r0+orr]   = u;
  *(bf16x8*)&op[(long)(c0+oc)*R + r0+orr+8] = v;
}

__global__ __launch_bounds__(256)
void scalar_proj_kernel(const float* __restrict__ x,
                        const float* __restrict__ wlr, const float* __restrict__ blr,
                        const float* __restrict__ wwd, const float* __restrict__ bwd,
                        const float* __restrict__ lbl, const float* __restrict__ lbw,
                        float* __restrict__ lr, float* __restrict__ lw)
{
  const int row  = blockIdx.x*4 + (threadIdx.x >> 6);
  const int lane = threadIdx.x & 63;
  const float4 a = ((const float4*)(x + (long)row*256))[lane];
  const float4 u = ((const float4*)wlr)[lane];
  const float4 w = ((const float4*)wwd)[lane];
  float d1 = a.x*u.x + a.y*u.y + a.z*u.z + a.w*u.w;
  float d2 = a.x*w.x + a.y*w.y + a.z*w.z + a.w*w.w;
  #pragma unroll
  for (int off=32; off; off>>=1) {
    d1 += __shfl_down(d1, off);
    d2 += __shfl_down(d2, off);
  }
  if (lane == 0) {
    float s1 = 1.f/(1.f+expf(-(d1 + blr[0])));
    lr[row] = expf(lbl[0]) * s1;
    float s2 = 1.f/(1.f+expf(-(d2 + bwd[0])));
    lw[row] = logf(1.f - expf(lbw[0]) * s2);
  }
}

// blocks 0..3: per-batch fp64 scan + derived; block 4: bias concat
__global__ __launch_bounds__(256)
void cumsum_kernel(const float* __restrict__ lw, const float* __restrict__ lr,
                   double* __restrict__ cd, float* __restrict__ wdc,
                   float* __restrict__ se1, float* __restrict__ se2, int L,
                   const float* __restrict__ bq, const float* __restrict__ bk,
                   const float* __restrict__ bv, float* __restrict__ bqkv)
{
  const int b = blockIdx.x;
  const int t = threadIdx.x;
  if (b == 4) {
    for (int i = t; i < 768; i += 256)
      bqkv[i] = (i<256) ? bq[i] : ((i<512) ? bk[i-256] : bv[i-512]);
    return;
  }
  const float* lwb = lw + (long)b*L;
  __shared__ double sum_s[256];
  double loc[8];
  double s = 0.0;
  #pragma unroll
  for (int i=0;i<8;i++){ s += (double)lwb[t*8+i]; loc[i] = s; }
  sum_s[t] = s;
  __syncthreads();
  for (int off=1; off<256; off<<=1){
    double v = 0.0;
    if (t >= off) v = sum_s[t-off];
    __syncthreads();
    sum_s[t] += v;
    __syncthreads();
  }
  const double prefix = (t > 0) ? sum_s[t-1] : 0.0;
  const double total  = sum_s[255];
  #pragma unroll
  for (int i=0;i<8;i++){
    double c = prefix + loc[i];
    long idx = (long)b*L + t*8 + i;
    cd[idx]  = c;
    wdc[idx] = (float)exp(c);
    double e = exp(total - c);
    se1[idx] = (float)(-e);
    se2[idx] = (float)(-e) * lr[idx];
  }
}

extern "C" void kernel_launch(void* const* d_in, const int* in_sizes, int n_in,
                              void* d_out, int out_size, void* d_ws, size_t ws_size,
                              hipStream_t stream)
{
  const int Bn = 4, L = 2048, D = 256, H = 512;
  const long LD = (long)L*D, LH = (long)L*H, HD = (long)H*D;

  const float* x   = (const float*)d_in[0];
  const float* W1  = (const float*)d_in[1];
  const float* W2  = (const float*)d_in[2];
  const float* Wq  = (const float*)d_in[3];
  const float* bq  = (const float*)d_in[4];
  const float* Wk  = (const float*)d_in[5];
  const float* bk  = (const float*)d_in[6];
  const float* Wv  = (const float*)d_in[7];
  const float* bv  = (const float*)d_in[8];
  const float* wlr = (const float*)d_in[9];
  const float* blr = (const float*)d_in[10];
  const float* wwd = (const float*)d_in[11];
  const float* bwd = (const float*)d_in[12];
  const float* lbl = (const float*)d_in[13];
  const float* lbw = (const float*)d_in[14];
  (void)in_sizes; (void)n_in; (void)out_size; (void)ws_size;

  float* out0 = (float*)d_out;            // Z2_      [B,L,D]
  float* out1 = out0 + (long)Bn*LD;       // W1_next  [B,H,D]
  float* out2 = out1 + (long)Bn*HD;       // W2_next  [B,D,H]

  char* wsp = (char*)d_ws;
  size_t off = 0;
  auto alloc = [&](size_t bytes)->void*{
    void* p = wsp + off; off += (bytes + 255) & ~(size_t)255; return p;
  };
  bf16* xb    = (bf16*)alloc((size_t)Bn*LD*2);
  bf16* Wqkvt = (bf16*)alloc((size_t)3*D*D*2);
  float* bqkv = (float*)alloc((size_t)3*D*4);
  bf16* W1b  = (bf16*)alloc((size_t)Bn*HD*2);
  bf16* W2b  = (bf16*)alloc((size_t)Bn*HD*2);
  bf16* W2t  = (bf16*)alloc((size_t)Bn*HD*2);
  bf16* Qb   = (bf16*)alloc((size_t)Bn*LD*2);
  bf16* Kb   = (bf16*)alloc((size_t)Bn*LD*2);
  bf16* Kt   = (bf16*)alloc((size_t)Bn*LD*2);
  float* Vf  = (float*)alloc((size_t)Bn*LD*4);
  bf16* Z1b  = (bf16*)alloc((size_t)Bn*LH*2);
  bf16* X2b  = (bf16*)alloc((size_t)Bn*LH*2);
  bf16* X2t  = (bf16*)alloc((size_t)Bn*LH*2);
  bf16* gZb  = (bf16*)alloc((size_t)Bn*LD*2);
  bf16* gZt  = (bf16*)alloc((size_t)Bn*LD*2);
  bf16* A1b  = (bf16*)alloc((size_t)Bn*LH*2);
  bf16* A1t  = (bf16*)alloc((size_t)Bn*LH*2);
  bf16* X2_b = (bf16*)alloc((size_t)Bn*LH*2);
  bf16* Pb1  = (bf16*)alloc((size_t)Bn*32*3*64*128*2);
  bf16* Pb2  = (bf16*)alloc((size_t)Bn*32*3*64*128*2);
  float* lrb = (float*)alloc((size_t)Bn*L*4);
  float* lwb = (float*)alloc((size_t)Bn*L*4);
  float* wdc = (float*)alloc((size_t)Bn*L*4);
  float* se1 = (float*)alloc((size_t)Bn*L*4);
  float* se2 = (float*)alloc((size_t)Bn*L*4);
  double* cdb = (double*)alloc((size_t)Bn*L*8);

  auto run128 = [&](const MArgs& g, int Z){
    dim3 grid(g.M/128, g.N/64, Z);
    mfma_gemm128<<<grid, 256, 0, stream>>>(g);
  };
  auto run64 = [&](const MArgs& g, int Z){
    dim3 grid(g.M/64, g.N/64, Z);
    mfma_gemm64<<<grid, 256, 0, stream>>>(g);
  };

  // zero out0 (cons2 accumulates atomically)
  hipMemsetAsync(out0, 0, (size_t)Bn*LD*4, stream);

  // ---- front matter (merged)
  conv_multi<<<dim3(1024,3), 256, 0, stream>>>(x, xb, Bn*LD, W1, W1b, Bn*HD, W2, W2b, Bn*HD);
  transpose_multi<<<dim3(4,8,7), 256, 0, stream>>>(Wq, Wk, Wv, Wqkvt, W2, W2t, HD);
  scalar_proj_kernel<<<dim3(Bn*L/4), 256, 0, stream>>>(x, wlr, blr, wwd, bwd, lbl, lbw, lrb, lwb);
  cumsum_kernel<<<dim3(5), 256, 0, stream>>>(lwb, lrb, cdb, wdc, se1, se2, L, bq, bk, bv, bqkv);

  // ---- fused QKV (M = B*L, N = 768); Kt via Ct
  {
    MArgs g{}; g.A = xb; g.lda = D; g.B = Wqkvt; g.ldb = D;
    g.M = Bn*L; g.N = 3*D; g.K = D; g.mode = 11; g.ldc = 0;
    g.Q = Qb; g.Ko = Kb; g.Vo = Vf; g.bqkv = bqkv;
    g.Ct = Kt; g.sCt = LD; g.ldct = L;
    run128(g, 1);
  }
  // ---- Z1 = K.W1^T ; X2 = silu(Z1); X2t via Ct
  {
    MArgs g{}; g.A = Kb; g.lda = D; g.sA = LD; g.B = W1b; g.ldb = D; g.sB = HD;
    g.M = L; g.N = H; g.K = D; g.mode = 1; g.ldc = H;
    g.Cb = Z1b; g.sCb = LH; g.Cb2 = X2b; g.sCb2 = LH;
    g.Ct = X2t; g.sCt = LH; g.ldct = L; run64(g, Bn);
  }
  // ---- gZ2 = X2.W2^T - V; gZt via Ct
  {
    MArgs g{}; g.A = X2b; g.lda = H; g.sA = LH; g.B = W2b; g.ldb = H; g.sB = HD;
    g.M = L; g.N = D; g.K = H; g.mode = 2; g.ldc = D;
    g.auxf = Vf; g.ldax = D; g.sAuxf = LD; g.Cb = gZb; g.sCb = LD;
    g.Ct = gZt; g.sCt = LD; g.ldct = L; run64(g, Bn);
  }
  // ---- A1 = silu_bwd(Z1)*(gZ2.W2)*lr; A1t via Ct
  {
    MArgs g{}; g.A = gZb; g.lda = D; g.sA = LD; g.B = W2t; g.ldb = D; g.sB = HD;
    g.M = L; g.N = H; g.K = D; g.mode = 3; g.ldc = H;
    g.auxb = Z1b; g.ldax = H; g.sAuxb = LH; g.rowv = lrb; g.sRowv = L;
    g.Cb = A1b; g.sCb = LH;
    g.Ct = A1t; g.sCt = LH; g.ldct = L; run64(g, Bn);
  }
  // ---- P1 banded tiles: P1[m,l] = -(Q[m].K[l])*exp(cd[m]-cd[l])*(l<=m)
  {
    PArgs p{};
    p.A = Qb; p.sA = LD; p.B1 = Kb; p.sB1 = LD;
    p.cd = cdb; p.sCd = L; p.P = Pb1;
    pgen<4,0><<<dim3(32,3,Bn), 256, 0, stream>>>(p);
  }
  // ---- cons1: X2_ = silu( wdc[m]*(Q.W1^T) + sum P1.A1t )
  {
    CArgs c{};
    c.A = Qb; c.sA = LD; c.W = W1b; c.sW = HD;
    c.P = Pb1; c.B2 = A1t; c.sB2 = LH; c.ldb2 = L;
    c.cd = cdb; c.sCd = L; c.wdc = wdc; c.sWdc = L;
    c.Cb = X2_b; c.sCb = LH; c.ldc = H;
    cons<4,1,0><<<dim3(32, H/128, Bn), 256, 0, stream>>>(c);
  }
  // ---- P2 banded tiles: P2[m,l] = -(X2_[m].X2[l])*exp(cd[m]-cd[l])*lr[l]*(l<=m)
  {
    PArgs p{};
    p.A = X2_b; p.sA = LH; p.B1 = X2b; p.sB1 = LH;
    p.cd = cdb; p.sCd = L; p.lrv = lrb; p.sLr = L; p.P = Pb2;
    pgen<8,1><<<dim3(32,3,Bn), 256, 0, stream>>>(p);
  }
  // ---- cons2: out0 += wdc[m]*(X2_.W2^T) + sum P2.gZt   (z-split, atomic)
  {
    CArgs c{};
    c.A = X2_b; c.sA = LH; c.W = W2b; c.sW = HD;
    c.P = Pb2; c.B2 = gZt; c.sB2 = LD; c.ldb2 = L;
    c.cd = cdb; c.sCd = L; c.wdc = wdc; c.sWdc = L;
    c.Cf = out0; c.sCf = LD; c.ldc = D;
    cons<8,0,1><<<dim3(32, D/128, Bn*2), 256, 0, stream>>>(c);
  }
  // ---- W1_next + W2_next in one launch
  {
    MArgs g1{}; g1.A = A1t; g1.lda = L; g1.sA = LH; g1.B = Kt; g1.ldb = L; g1.sB = LD;
    g1.M = H; g1.N = D; g1.K = L; g1.mode = 10; g1.ldc = D;
    g1.ks = se1; g1.sKs = L; g1.cd = cdb; g1.sCd = L;
    g1.auxf = W1; g1.ldax = D; g1.sAuxf = HD; g1.clp = wdc + (L-1); g1.sClp = L;
    g1.Cf = out1; g1.sCf = HD;

    MArgs g2{}; g2.A = gZt; g2.lda = L; g2.sA = LD; g2.B = X2t; g2.ldb = L; g2.sB = LH;
    g2.M = D; g2.N = H; g2.K = L; g2.mode = 10; g2.ldc = H;
    g2.ks = se2; g2.sKs = L; g2.cd = cdb; g2.sCd = L;
    g2.auxf = W2; g2.ldax = H; g2.sAuxf = HD; g2.clp = wdc + (L-1); g2.sClp = L;
    g2.Cf = out2; g2.sCf = HD;

    wnext_gemm<<<dim3(4,8,8), 256, 0, stream>>>(g1, g2);
  }
}